// Round 1
// baseline (186.956 us; speedup 1.0000x reference)
//
#include <hip/hip_runtime.h>
#include <hip/hip_bf16.h>
#include <stdint.h>

// HMQSoftmax: out = bf16(bf16(e*r)*r) with e = 2^floor(x*log2e) (bf16-exact),
// r = quake-isqrt_bf16(bf16(f32_sum(e))) per row of 2048.
//
// Numerics: jnp.sum on bf16 accumulates in f32 (upcast_f16_for_computation),
// rounded to bf16 once -> we tree-reduce in f32 (order-insensitive: addends
// are exact powers of two). All bf16 multiplies/subtracts are emulated via
// exact f32 arithmetic + manual RNE round to bf16 (product of two bf16 is
// exact in f32: 8x8 mantissa bits <= 24).

#define INV_LN2F 1.4426950408889634f

__device__ __forceinline__ float rne_bf16(float f) {
    // round f32 -> bf16 (round-to-nearest-even), return as f32 value
    uint32_t u = __float_as_uint(f);
    uint32_t r = (u + 0x7FFFu + ((u >> 16) & 1u)) & 0xFFFF0000u;
    return __uint_as_float(r);
}

__global__ __launch_bounds__(256) void hmq_softmax_kernel(
        const float* __restrict__ x, float* __restrict__ out) {
    const int row = blockIdx.x;
    const int t = threadIdx.x;
    const size_t base = (size_t)row * 2048;

    const float4* __restrict__ xr = (const float4*)(x + base);
    float4 a = xr[t];           // elements 4t .. 4t+3
    float4 b = xr[256 + t];     // elements 1024+4t .. 1024+4t+3

    float v[8] = {a.x, a.y, a.z, a.w, b.x, b.y, b.z, b.w};
    float e[8];
    float partial = 0.0f;
    #pragma unroll
    for (int k = 0; k < 8; ++k) {
        float m = floorf(v[k] * INV_LN2F);   // f32 mul + floor, matches jax
        float ev = ldexpf(1.0f, (int)m);     // exact 2^m (bf16-exact value)
        e[k] = ev;
        partial += ev;                        // f32 accumulation (jnp upcast)
    }

    // wave64 butterfly reduce in f32
    #pragma unroll
    for (int off = 32; off > 0; off >>= 1)
        partial += __shfl_xor(partial, off, 64);

    __shared__ float ws[4];
    __shared__ float rsh;
    const int wave = t >> 6;
    if ((t & 63) == 0) ws[wave] = partial;
    __syncthreads();
    if (t == 0) {
        float s  = (ws[0] + ws[1]) + (ws[2] + ws[3]);
        float sb = rne_bf16(s);              // exp_sum -> bf16 (single round)

        // _isqrt_bf16, bit-exact emulation
        uint16_t bits = (uint16_t)(__float_as_uint(sb) >> 16);
        int16_t  i    = (int16_t)bits;
        i = (int16_t)(24375 - (i >> 1));     // MAGIC - (i>>1), int16 wrap
        float y   = __uint_as_float(((uint32_t)(uint16_t)i) << 16);
        float y2  = rne_bf16(y * y);
        float xh  = rne_bf16(sb * 0.5f);     // exact anyway
        float mul = rne_bf16(xh * y2);
        float sub = rne_bf16(1.5f - mul);    // exact f32 diff, then bf16 round
        rsh = rne_bf16(y * sub);             // one Newton step
    }
    __syncthreads();
    const float r = rsh;

    float o[8];
    #pragma unroll
    for (int k = 0; k < 8; ++k) {
        float tt = rne_bf16(e[k] * r);       // exp_x * r  (bf16 round; exact shift)
        o[k]     = rne_bf16(tt * r);         // * r again  (bf16 round)
    }

    float4* __restrict__ orow = (float4*)(out + base);
    orow[t]       = make_float4(o[0], o[1], o[2], o[3]);
    orow[256 + t] = make_float4(o[4], o[5], o[6], o[7]);
}

extern "C" void kernel_launch(void* const* d_in, const int* in_sizes, int n_in,
                              void* d_out, int out_size, void* d_ws, size_t ws_size,
                              hipStream_t stream) {
    (void)n_in; (void)d_ws; (void)ws_size; (void)out_size;
    const float* x = (const float*)d_in[0];
    float* out = (float*)d_out;
    const int rows = in_sizes[0] / 2048;     // 65536 rows of 2048
    hmq_softmax_kernel<<<rows, 256, 0, stream>>>(x, out);
}

// Round 2
// 176.630 us; speedup vs baseline: 1.0585x; 1.0585x over previous
//
#include <hip/hip_runtime.h>
#include <hip/hip_bf16.h>
#include <stdint.h>

// HMQSoftmax: out = bf16(bf16(e*r)*r) with e = 2^floor(x*log2e) (bf16-exact),
// r = quake-isqrt_bf16(bf16(f32_sum(e))) per row of 2048.
//
// R2 structure: one wave64 per row (4 rows per 256-thread block).
//  - reduction = 6 x shfl_xor, no LDS, no __syncthreads
//  - every lane computes the (wave-uniform) bf16 isqrt redundantly
//  - nontemporal float4 loads/stores (1 GB streaming footprint > L3)
// Numerics identical to R1 (passed, absmax 4.9e-4 vs thr 1.04e-3):
// f32 tree-sum (order-insensitive: addends are exact powers of two), all
// bf16 ops emulated via exact f32 arithmetic + manual RNE round.

#define INV_LN2F 1.4426950408889634f

typedef float f32x4 __attribute__((ext_vector_type(4)));

__device__ __forceinline__ float rne_bf16(float f) {
    uint32_t u = __float_as_uint(f);
    uint32_t r = (u + 0x7FFFu + ((u >> 16) & 1u)) & 0xFFFF0000u;
    return __uint_as_float(r);
}

__global__ __launch_bounds__(256) void hmq_softmax_kernel(
        const float* __restrict__ x, float* __restrict__ out) {
    const int wave = threadIdx.x >> 6;
    const int lane = threadIdx.x & 63;
    const size_t row = (size_t)blockIdx.x * 4 + wave;
    const size_t base = row * 2048;

    const f32x4* __restrict__ xr = (const f32x4*)(x + base);
    f32x4* __restrict__ orow = (f32x4*)(out + base);

    // load 8 x float4 per lane (lane-contiguous chunks of 64 float4)
    f32x4 v[8];
    #pragma unroll
    for (int c = 0; c < 8; ++c)
        v[c] = __builtin_nontemporal_load(&xr[c * 64 + lane]);

    float e[32];
    float partial = 0.0f;
    #pragma unroll
    for (int c = 0; c < 8; ++c) {
        #pragma unroll
        for (int k = 0; k < 4; ++k) {
            float m  = floorf(v[c][k] * INV_LN2F);  // f32 mul + floor (matches jax)
            float ev = ldexpf(1.0f, (int)m);        // exact 2^m
            e[c * 4 + k] = ev;
            partial += ev;                           // f32 accumulation
        }
    }

    // wave64 butterfly reduce (f32); all lanes end with the full row sum
    #pragma unroll
    for (int off = 32; off > 0; off >>= 1)
        partial += __shfl_xor(partial, off, 64);

    // bf16 quake isqrt, computed redundantly per lane (wave-uniform)
    float sb = rne_bf16(partial);                    // exp_sum -> bf16
    uint16_t bits = (uint16_t)(__float_as_uint(sb) >> 16);
    int16_t  i    = (int16_t)bits;
    i = (int16_t)(24375 - (i >> 1));                 // MAGIC - (i>>1), int16 wrap
    float y   = __uint_as_float(((uint32_t)(uint16_t)i) << 16);
    float y2  = rne_bf16(y * y);
    float xh  = rne_bf16(sb * 0.5f);
    float mul = rne_bf16(xh * y2);
    float sub = rne_bf16(1.5f - mul);
    float r   = rne_bf16(y * sub);                   // one Newton step

    #pragma unroll
    for (int c = 0; c < 8; ++c) {
        f32x4 o;
        #pragma unroll
        for (int k = 0; k < 4; ++k) {
            float tt = rne_bf16(e[c * 4 + k] * r);
            o[k]     = rne_bf16(tt * r);
        }
        __builtin_nontemporal_store(o, &orow[c * 64 + lane]);
    }
}

extern "C" void kernel_launch(void* const* d_in, const int* in_sizes, int n_in,
                              void* d_out, int out_size, void* d_ws, size_t ws_size,
                              hipStream_t stream) {
    (void)n_in; (void)d_ws; (void)ws_size; (void)out_size;
    const float* x = (const float*)d_in[0];
    float* out = (float*)d_out;
    const int rows = in_sizes[0] / 2048;             // 65536 rows
    hmq_softmax_kernel<<<rows / 4, 256, 0, stream>>>(x, out);
}